// Round 3
// baseline (311.869 us; speedup 1.0000x reference)
//
#include <hip/hip_runtime.h>
#include <math.h>

// InfoNCE, exact JAX threefry2x32 negative-sampling reproduction.
// I=4096, E=16384, D=64.
//
// R3 design: DECOUPLE the adj stream (memory-bound) from the threefry
// stream (pure VALU, no memory input). One heterogeneous dispatch mixes
// both block roles across CUs (blockIdx%3: 2 pos-blocks : 1 cand-block)
// so HBM and VALU pipes overlap. A small finalize kernel does per-row
// rank + dots + loss from the ~100 surviving entries per row.

constexpr int D      = 64;
constexpr int PCAP   = 96;    // num_pos ~ Binom(16384,.002): mean 33, 11 sigma
constexpr int CCAP   = 192;   // bin-0 count ~ Binom(16384,1/256): mean 64, 16 sigma
constexpr int SELCAP = 256;

// JAX threefry2x32, key = (0, 42) from jax.random.key(42).
__device__ __forceinline__ void threefry2x32(unsigned x0, unsigned x1,
                                             unsigned& o0, unsigned& o1) {
  const unsigned ks0 = 0u;
  const unsigned ks1 = 42u;
  const unsigned ks2 = 0x1BD11BDAu ^ 0u ^ 42u;
  x0 += ks0; x1 += ks1;
#define TF_R(r) { x0 += x1; x1 = (x1 << (r)) | (x1 >> (32 - (r))); x1 ^= x0; }
  TF_R(13) TF_R(15) TF_R(26) TF_R(6)
  x0 += ks1; x1 += ks2 + 1u;
  TF_R(17) TF_R(29) TF_R(16) TF_R(24)
  x0 += ks2; x1 += ks0 + 2u;
  TF_R(13) TF_R(15) TF_R(26) TF_R(6)
  x0 += ks0; x1 += ks1 + 3u;
  TF_R(17) TF_R(29) TF_R(16) TF_R(24)
  x0 += ks1; x1 += ks2 + 4u;
  TF_R(13) TF_R(15) TF_R(26) TF_R(6)
  x0 += ks2; x1 += ks0 + 5u;
#undef TF_R
  o0 = x0; o1 = x1;
}

__device__ __forceinline__ float dot_sim(const float* __restrict__ ent, int e,
                                         const float* itemn) {
  const float4* er = (const float4*)(ent + ((size_t)e << 6));
  float dot = 0.f, ss = 0.f;
#pragma unroll
  for (int q = 0; q < 16; ++q) {
    float4 f = er[q];
    dot += itemn[4 * q + 0] * f.x + itemn[4 * q + 1] * f.y +
           itemn[4 * q + 2] * f.z + itemn[4 * q + 3] * f.w;
    ss += f.x * f.x + f.y * f.y + f.z * f.z + f.w * f.w;
  }
  return dot * (1.0f / sqrtf(ss));
}

__device__ __forceinline__ float block_max(float v, float* wred, int t) {
#pragma unroll
  for (int off = 32; off; off >>= 1) v = fmaxf(v, __shfl_xor(v, off, 64));
  __syncthreads();
  if ((t & 63) == 0) wred[t >> 6] = v;
  __syncthreads();
  return fmaxf(fmaxf(wred[0], wred[1]), fmaxf(wred[2], wred[3]));
}

__device__ __forceinline__ float block_sum(float v, float* wred, int t) {
#pragma unroll
  for (int off = 32; off; off >>= 1) v += __shfl_xor(v, off, 64);
  __syncthreads();
  if ((t & 63) == 0) wred[t >> 6] = v;
  __syncthreads();
  return wred[0] + wred[1] + wred[2] + wred[3];
}

// ---------------- workspace-based fast path ----------------

__global__ __launch_bounds__(256) void ws_zero(int* pos_cnt, int* cand_cnt,
                                               double* accum, int* paircnt, int I) {
  int t = blockIdx.x * 256 + threadIdx.x;
  if (t < I) { pos_cnt[t] = 0; cand_cnt[t] = 0; }
  if (t == 0) { *accum = 0.0; *paircnt = 0; }
}

// Heterogeneous dispatch: blockIdx%3 in {0,1} -> pos-extract (memory-bound),
// ==2 -> cand-gen (pure VALU, no memory input). Interleaving mixes roles per CU.
__global__ __launch_bounds__(256) void phase1(
    const int* __restrict__ adj, int I, int E,
    int* __restrict__ pos_cnt, int* __restrict__ pos_idx,
    int* __restrict__ cand_cnt, int* __restrict__ cand_idx,
    unsigned* __restrict__ cand_key) {
  const int t = threadIdx.x;
  const int r3 = blockIdx.x % 3;
  const int g  = blockIdx.x / 3;

  if (r3 < 2) {
    // ---- positive extraction for row (2g + r3): pure adj stream ----
    const int row = g * 2 + r3;
    __shared__ int s_np;
    __shared__ int s_pos[PCAP];
    if (t == 0) s_np = 0;
    __syncthreads();
    const int4* a = (const int4*)(adj + (size_t)row * E);
    const int nvec = E >> 2;
    for (int v = t; v < nvec; v += 256) {
      int4 x = a[v];
      int e0 = v * 4;
      if (x.x > 0) { int s = atomicAdd(&s_np, 1); if (s < PCAP) s_pos[s] = e0; }
      if (x.y > 0) { int s = atomicAdd(&s_np, 1); if (s < PCAP) s_pos[s] = e0 + 1; }
      if (x.z > 0) { int s = atomicAdd(&s_np, 1); if (s < PCAP) s_pos[s] = e0 + 2; }
      if (x.w > 0) { int s = atomicAdd(&s_np, 1); if (s < PCAP) s_pos[s] = e0 + 3; }
    }
    __syncthreads();
    const int np = s_np;  // true count; >PCAP triggers finalize fallback
    if (t == 0) pos_cnt[row] = np;
    const int npc = min(np, PCAP);
    for (int i = t; i < npc; i += 256) pos_idx[(size_t)row * PCAP + i] = s_pos[i];
  } else {
    // ---- candidate gen for row pair (g, g+I/2): NO memory input ----
    const int iA = g;
    const unsigned HALF = (unsigned)(I >> 1) * (unsigned)E;  // 2^25
    const unsigned base = (unsigned)iA * (unsigned)E;
    __shared__ int s_nc[2];
    __shared__ int s_ci[2][CCAP];
    __shared__ unsigned s_ck[2][CCAP];
    if (t < 2) s_nc[t] = 0;
    __syncthreads();
#define CAPP(bits, half, ee)                                              \
    if (((bits) >> 24) == 0u) {                                           \
      int s_ = atomicAdd(&s_nc[half], 1);                                 \
      if (s_ < CCAP) { s_ci[half][s_] = (int)(ee); s_ck[half][s_] = (bits) >> 9; } \
    }
    for (int it = 0; it < 16; ++it) {
      const unsigned e0 = (unsigned)(it * 1024 + t);
      unsigned a0, a1, b0, b1, c0, c1, d0, d1;
      threefry2x32(base + e0,       base + e0 + HALF,       a0, a1);
      threefry2x32(base + e0 + 256, base + e0 + 256 + HALF, b0, b1);
      threefry2x32(base + e0 + 512, base + e0 + 512 + HALF, c0, c1);
      threefry2x32(base + e0 + 768, base + e0 + 768 + HALF, d0, d1);
      CAPP(a0, 0, e0)       CAPP(a1, 1, e0)
      CAPP(b0, 0, e0 + 256) CAPP(b1, 1, e0 + 256)
      CAPP(c0, 0, e0 + 512) CAPP(c1, 1, e0 + 512)
      CAPP(d0, 0, e0 + 768) CAPP(d1, 1, e0 + 768)
    }
#undef CAPP
    __syncthreads();
    const int rowA = iA, rowB = iA + (I >> 1);
    const int ncA = s_nc[0], ncB = s_nc[1];
    if (t == 0) { cand_cnt[rowA] = ncA; cand_cnt[rowB] = ncB; }
    const int ncAc = min(ncA, CCAP), ncBc = min(ncB, CCAP);
    for (int i = t; i < ncAc; i += 256) {
      cand_idx[(size_t)rowA * CCAP + i] = s_ci[0][i];
      cand_key[(size_t)rowA * CCAP + i] = s_ck[0][i];
    }
    for (int i = t; i < ncBc; i += 256) {
      cand_idx[(size_t)rowB * CCAP + i] = s_ci[1][i];
      cand_key[(size_t)rowB * CCAP + i] = s_ck[1][i];
    }
  }
}

// One block per row: filter + exact rank + dots + loss.
__global__ __launch_bounds__(256) void finalize(
    const float* __restrict__ item, const float* __restrict__ ent,
    const int* __restrict__ adj, int I, int E,
    const int* __restrict__ pos_cnt, const int* __restrict__ pos_idx,
    const int* __restrict__ cand_cnt, const int* __restrict__ cand_idx,
    const unsigned* __restrict__ cand_key,
    double* __restrict__ accum, int* __restrict__ paircnt) {
  const int row = blockIdx.x;
  const int t = threadIdx.x;
  const int npos = pos_cnt[row];
  if (npos == 0) return;
  const int k = min(npos, E - npos);  // == npos here (E-npos >> npos)

  __shared__ int s_pos[PCAP];
  __shared__ int s_ci[CCAP];
  __shared__ unsigned s_ck[CCAP];
  __shared__ int s_sel[SELCAP];
  __shared__ int s_hist[256];
  __shared__ float s_itemn[D];
  __shared__ float s_wred[4];
  __shared__ int s_negc, s_nsel, s_bbin, s_cbef;
  __shared__ float s_scale;

  int nc = cand_cnt[row];
  bool fallback = (npos > PCAP) || (nc > CCAP);

  if (!fallback) {
    for (int i = t; i < npos; i += 256) s_pos[i] = pos_idx[(size_t)row * PCAP + i];
    for (int i = t; i < nc; i += 256) {
      s_ci[i] = cand_idx[(size_t)row * CCAP + i];
      s_ck[i] = cand_key[(size_t)row * CCAP + i];
    }
    if (t == 0) s_negc = 0;
    __syncthreads();
    // sentinel-out candidates that are positives (cand stream is adj-blind)
    for (int i = t; i < nc; i += 256) {
      int e = s_ci[i];
      bool isPos = false;
      for (int p = 0; p < npos; ++p) isPos |= (s_pos[p] == e);
      if (isPos) s_ck[i] = 0xFFFFFFFFu;
      else atomicAdd(&s_negc, 1);
    }
    __syncthreads();
    if (s_negc < k) fallback = true;  // k-th smallest not guaranteed in bin 0
  }

  if (t == 0) s_nsel = 0;
  __syncthreads();

  // threefry params for this row
  const unsigned HALF = (unsigned)(I >> 1) * (unsigned)E;
  const bool hi = (row >= (I >> 1));
  const unsigned base = (unsigned)(hi ? row - (I >> 1) : row) * (unsigned)E;

  if (!fallback) {
    // exact rank among bin-0 candidates, stable tie-break (key, idx)
    for (int i = t; i < nc; i += 256) {
      unsigned mk = s_ck[i];
      if (mk == 0xFFFFFFFFu) continue;
      int mi = s_ci[i];
      int rank = 0;
      for (int c = 0; c < nc; ++c) {
        unsigned ck = s_ck[c];
        int ci = s_ci[c];
        rank += (ck < mk || (ck == mk && ci < mi)) ? 1 : 0;
      }
      if (rank < k) {
        int s = atomicAdd(&s_nsel, 1);
        if (s < SELCAP) s_sel[s] = mi;
      }
    }
  } else {
    // ---- rare exact fallback: full row rescan with 256-bin histogram ----
    s_hist[t] = 0;
    if (t == 0) s_negc = 0;
    __syncthreads();
    const int* adjR = adj + (size_t)row * E;
    for (int e = t; e < E; e += 256) {
      if (adjR[e] > 0) continue;
      unsigned o0, o1;
      threefry2x32(base + (unsigned)e, base + (unsigned)e + HALF, o0, o1);
      atomicAdd(&s_hist[(hi ? o1 : o0) >> 24], 1);
    }
    __syncthreads();
    if (t == 0) {
      int cum = 0, b = 0;
      while (b < 255 && cum + s_hist[b] < k) { cum += s_hist[b]; ++b; }
      s_bbin = b; s_cbef = cum;
    }
    __syncthreads();
    const int b = s_bbin;
    for (int e = t; e < E; e += 256) {
      if (adjR[e] > 0) continue;
      unsigned o0, o1;
      threefry2x32(base + (unsigned)e, base + (unsigned)e + HALF, o0, o1);
      unsigned bits = hi ? o1 : o0;
      int b8 = (int)(bits >> 24);
      if (b8 < b) {
        int s = atomicAdd(&s_nsel, 1);
        if (s < SELCAP) s_sel[s] = e;
      } else if (b8 == b) {
        int s = atomicAdd(&s_negc, 1);
        if (s < CCAP) { s_ci[s] = e; s_ck[s] = bits >> 9; }
      }
    }
    __syncthreads();
    const int ncf = min(s_negc, CCAP);
    const int rneed = k - s_cbef;
    for (int i = t; i < ncf; i += 256) {
      unsigned mk = s_ck[i];
      int mi = s_ci[i];
      int rank = 0;
      for (int c = 0; c < ncf; ++c) {
        unsigned ck = s_ck[c];
        int ci = s_ci[c];
        rank += (ck < mk || (ck == mk && ci < mi)) ? 1 : 0;
      }
      if (rank < rneed) {
        int s = atomicAdd(&s_nsel, 1);
        if (s < SELCAP) s_sel[s] = mi;
      }
    }
  }

  // item row scale = 1/||item|| / T
  float iv = 0.f;
  if (t < D) iv = item[(size_t)row * D + t];
  if (t < 64) {
    float ss = iv * iv;
#pragma unroll
    for (int off = 32; off; off >>= 1) ss += __shfl_xor(ss, off, 64);
    if (t == 0) s_scale = (1.0f / sqrtf(ss)) * (1.0f / 0.07f);
  }
  __syncthreads();  // also closes the rank-append section
  if (t < D) s_itemn[t] = iv * s_scale;
  __syncthreads();
  const int nsel = min(s_nsel, SELCAP);  // == k

  float myv = (t < nsel) ? dot_sim(ent, s_sel[t], s_itemn) : -INFINITY;
  const float m = block_max(myv, s_wred, t);
  float v2 = (t < nsel) ? expf(myv - m) : 0.f;
  const float S = block_sum(v2, s_wred, t);

  float lp = 0.f;
  if (!fallback) {
    if (t < npos) {
      float sp = dot_sim(ent, s_pos[t], s_itemn);
      float pm = fmaxf(sp, m);
      lp = logf(expf(sp - pm) + S * expf(m - pm)) + pm - sp;
    }
  } else {
    const int* adjR = adj + (size_t)row * E;
    for (int e = t; e < E; e += 256) {
      if (adjR[e] > 0) {
        float sp = dot_sim(ent, e, s_itemn);
        float pm = fmaxf(sp, m);
        lp += logf(expf(sp - pm) + S * expf(m - pm)) + pm - sp;
      }
    }
  }
  const float rowloss = block_sum(lp, s_wred, t);
  if (t == 0) {
    atomicAdd(accum, (double)rowloss);
    atomicAdd(paircnt, npos);
  }
}

// ---------------- monolithic fallback (R2) if ws too small ----------------

__global__ __launch_bounds__(256) void infonce_mono(
    const float* __restrict__ item, const float* __restrict__ ent,
    const int* __restrict__ adj, int I, int E,
    double* __restrict__ accum, int* __restrict__ paircnt) {
  const int t = threadIdx.x;
  const int halfI = I >> 1;
  const int iA = blockIdx.x;
  const int iB = iA + halfI;
  const unsigned HALF = (unsigned)halfI * (unsigned)E;
  const unsigned baseA = (unsigned)iA * (unsigned)E;

  __shared__ int s_pos[2][PCAP];
  __shared__ int s_cidx[2][CCAP];
  __shared__ unsigned s_ckey[2][CCAP];
  __shared__ int s_sel[SELCAP];
  __shared__ int s_hist[256];
  __shared__ float s_itemn[D];
  __shared__ float s_wred[4];
  __shared__ int s_np[2], s_nc[2];
  __shared__ int s_nsel, s_bbin, s_cbef, s_fnc;
  __shared__ float s_scale;

  if (t < 2) { s_np[t] = 0; s_nc[t] = 0; }
  __syncthreads();

  const int nvec = E >> 2;
  const int4* adjA = (const int4*)(adj + (size_t)iA * E);
  const int4* adjB = (const int4*)(adj + (size_t)iB * E);
  for (int v = t; v < nvec; v += 256) {
    int4 a4 = adjA[v];
    int4 b4 = adjB[v];
    int av[4] = {a4.x, a4.y, a4.z, a4.w};
    int bv[4] = {b4.x, b4.y, b4.z, b4.w};
    unsigned e0 = (unsigned)v * 4u;
#pragma unroll
    for (int c = 0; c < 4; ++c) {
      unsigned o0, o1;
      threefry2x32(baseA + e0 + c, baseA + e0 + c + HALF, o0, o1);
      const int e = (int)(e0 + c);
      if (av[c] > 0) {
        int s = atomicAdd(&s_np[0], 1); if (s < PCAP) s_pos[0][s] = e;
      } else if ((o0 >> 24) == 0u) {
        int s = atomicAdd(&s_nc[0], 1);
        if (s < CCAP) { s_cidx[0][s] = e; s_ckey[0][s] = o0 >> 9; }
      }
      if (bv[c] > 0) {
        int s = atomicAdd(&s_np[1], 1); if (s < PCAP) s_pos[1][s] = e;
      } else if ((o1 >> 24) == 0u) {
        int s = atomicAdd(&s_nc[1], 1);
        if (s < CCAP) { s_cidx[1][s] = e; s_ckey[1][s] = o1 >> 9; }
      }
    }
  }
  __syncthreads();

  for (int r2 = 0; r2 < 2; ++r2) {
    const int row = r2 ? iB : iA;
    const int npos = min(s_np[r2], PCAP);
    const int k = min(npos, E - npos);
    if (npos > 0 && k > 0) {
      if (t == 0) s_nsel = 0;
      __syncthreads();
      int ncand = min(s_nc[r2], CCAP);
      int rneed = k;
      if (ncand < k) {
        s_hist[t] = 0;
        if (t == 0) s_fnc = 0;
        __syncthreads();
        const int* adjR = adj + (size_t)row * E;
        for (int e = t; e < E; e += 256) {
          if (adjR[e] > 0) continue;
          unsigned o0, o1;
          threefry2x32(baseA + (unsigned)e, baseA + (unsigned)e + HALF, o0, o1);
          atomicAdd(&s_hist[(r2 ? o1 : o0) >> 24], 1);
        }
        __syncthreads();
        if (t == 0) {
          int cum = 0, b = 0;
          while (b < 255 && cum + s_hist[b] < k) { cum += s_hist[b]; ++b; }
          s_bbin = b; s_cbef = cum;
        }
        __syncthreads();
        const int b = s_bbin;
        for (int e = t; e < E; e += 256) {
          if (adjR[e] > 0) continue;
          unsigned o0, o1;
          threefry2x32(baseA + (unsigned)e, baseA + (unsigned)e + HALF, o0, o1);
          unsigned bits = r2 ? o1 : o0;
          int b8 = (int)(bits >> 24);
          if (b8 < b) {
            int s = atomicAdd(&s_nsel, 1); if (s < SELCAP) s_sel[s] = e;
          } else if (b8 == b) {
            int s = atomicAdd(&s_fnc, 1);
            if (s < CCAP) { s_cidx[r2][s] = e; s_ckey[r2][s] = bits >> 9; }
          }
        }
        __syncthreads();
        ncand = min(s_fnc, CCAP);
        rneed = k - s_cbef;
      }
      for (int c0 = t; c0 < ncand; c0 += 256) {
        unsigned mykey = s_ckey[r2][c0];
        int myidx = s_cidx[r2][c0];
        int rank = 0;
        for (int c = 0; c < ncand; ++c) {
          unsigned ck = s_ckey[r2][c];
          int ci = s_cidx[r2][c];
          rank += (ck < mykey || (ck == mykey && ci < myidx)) ? 1 : 0;
        }
        if (rank < rneed) {
          int s = atomicAdd(&s_nsel, 1); if (s < SELCAP) s_sel[s] = myidx;
        }
      }
      float iv = 0.f;
      if (t < D) iv = item[(size_t)row * D + t];
      if (t < 64) {
        float ss = iv * iv;
#pragma unroll
        for (int off = 32; off; off >>= 1) ss += __shfl_xor(ss, off, 64);
        if (t == 0) s_scale = (1.0f / sqrtf(ss)) * (1.0f / 0.07f);
      }
      __syncthreads();
      if (t < D) s_itemn[t] = iv * s_scale;
      __syncthreads();
      const int nsel = min(s_nsel, SELCAP);
      float myv = (t < nsel) ? dot_sim(ent, s_sel[t], s_itemn) : -INFINITY;
      const float m = block_max(myv, s_wred, t);
      float v2 = (t < nsel) ? expf(myv - m) : 0.f;
      const float S = block_sum(v2, s_wred, t);
      float lp = 0.f;
      if (t < npos) {
        float sp = dot_sim(ent, s_pos[r2][t], s_itemn);
        float pm = fmaxf(sp, m);
        lp = logf(expf(sp - pm) + S * expf(m - pm)) + pm - sp;
      }
      const float rowloss = block_sum(lp, s_wred, t);
      if (t == 0) {
        atomicAdd(accum, (double)rowloss);
        atomicAdd(paircnt, npos);
      }
      __syncthreads();
    }
  }
}

__global__ void infonce_init(double* accum, int* cnt) {
  if (threadIdx.x == 0 && blockIdx.x == 0) { accum[0] = 0.0; cnt[0] = 0; }
}

__global__ void infonce_final(const double* __restrict__ accum,
                              const int* __restrict__ cnt,
                              float* __restrict__ out) {
  if (threadIdx.x == 0 && blockIdx.x == 0) {
    int n = cnt[0];
    out[0] = (n > 0) ? (float)(accum[0] / (double)n) : 0.f;
  }
}

extern "C" void kernel_launch(void* const* d_in, const int* in_sizes, int n_in,
                              void* d_out, int out_size, void* d_ws, size_t ws_size,
                              hipStream_t stream) {
  const float* item = (const float*)d_in[0];
  const float* ent  = (const float*)d_in[1];
  const int*   adj  = (const int*)d_in[2];
  const int I = in_sizes[0] / D;   // 4096
  const int E = in_sizes[1] / D;   // 16384

  double* accum   = (double*)d_ws;
  int*    paircnt = (int*)((char*)d_ws + 8);

  const size_t need = 16 + (size_t)I * 4 * 2 + (size_t)I * PCAP * 4 +
                      (size_t)I * CCAP * 8;
  if (ws_size >= need && (I % 2) == 0) {
    int*      pos_cnt  = (int*)((char*)d_ws + 16);
    int*      cand_cnt = pos_cnt + I;
    int*      pos_idx  = cand_cnt + I;
    int*      cand_idx = pos_idx + (size_t)I * PCAP;
    unsigned* cand_key = (unsigned*)(cand_idx + (size_t)I * CCAP);

    ws_zero<<<(I + 255) / 256, 256, 0, stream>>>(pos_cnt, cand_cnt, accum, paircnt, I);
    phase1<<<I + I / 2, 256, 0, stream>>>(adj, I, E, pos_cnt, pos_idx,
                                          cand_cnt, cand_idx, cand_key);
    finalize<<<I, 256, 0, stream>>>(item, ent, adj, I, E, pos_cnt, pos_idx,
                                    cand_cnt, cand_idx, cand_key, accum, paircnt);
    infonce_final<<<1, 64, 0, stream>>>(accum, paircnt, (float*)d_out);
  } else {
    infonce_init<<<1, 64, 0, stream>>>(accum, paircnt);
    infonce_mono<<<I / 2, 256, 0, stream>>>(item, ent, adj, I, E, accum, paircnt);
    infonce_final<<<1, 64, 0, stream>>>(accum, paircnt, (float*)d_out);
  }
}